// Round 4
// baseline (87.071 us; speedup 1.0000x reference)
//
#include <hip/hip_runtime.h>
#include <hip/hip_fp16.h>
#include <stdint.h>
#include <math.h>

#define BS    2
#define RAYS  514
#define NS    64
#define LSEQ  512
#define NF    257
#define HIDN  64
#define HID2  65          // 64 h-columns + 1 w-column (W_sig row = b_sig)
#define BSTR  67          // bucket row stride (67%32=3, coprime -> 2-way max)

#define TWO_PI_F 6.28318530717958647692f

__device__ __forceinline__ uint32_t rotl32(uint32_t x, int d){ return (x<<d)|(x>>(32-d)); }

__device__ __forceinline__ void tf_rounds4(uint32_t& x0, uint32_t& x1, int a, int b, int c, int d){
  x0+=x1; x1=rotl32(x1,a); x1^=x0;
  x0+=x1; x1=rotl32(x1,b); x1^=x0;
  x0+=x1; x1=rotl32(x1,c); x1^=x0;
  x0+=x1; x1=rotl32(x1,d); x1^=x0;
}

// Threefry-2x32, 20 rounds, matching jax._src.prng.threefry2x32
__device__ void threefry2x32(uint32_t k0, uint32_t k1, uint32_t x0, uint32_t x1,
                             uint32_t& o0, uint32_t& o1)
{
  const uint32_t ks2 = k0 ^ k1 ^ 0x1BD11BDAu;
  x0 += k0; x1 += k1;
  tf_rounds4(x0,x1,13,15,26,6);   x0+=k1;  x1+=ks2+1u;
  tf_rounds4(x0,x1,17,29,16,24);  x0+=ks2; x1+=k0+2u;
  tf_rounds4(x0,x1,13,15,26,6);   x0+=k0;  x1+=k1+3u;
  tf_rounds4(x0,x1,17,29,16,24);  x0+=k1;  x1+=ks2+4u;
  tf_rounds4(x0,x1,13,15,26,6);   x0+=ks2; x1+=k0+5u;
  o0 = x0; o1 = x1;
}

// Reproduces _ray_directions() for ray r (verified round 0).
__device__ void ray_dir(int r, float d[3])
{
  if (r >= 512) { d[0]=0.f; d[1]=0.f; d[2] = (r==512) ? 1.0f : -1.0f; return; }
  int i = r >> 4, j = r & 15;
  uint32_t o0, o1;
  threefry2x32(0u, 42u, 0u, (uint32_t)i, o0, o1);
  uint32_t bits = o0 ^ o1;
  float u = __uint_as_float((bits >> 9) | 0x3F800000u) - 1.0f;   // uniform [0,1)
  const float step = TWO_PI_F / 32.0f;
  float a = (float)i * step + step * u;
  float e = acosf(2.0f * ((float)(j+1) * (1.0f/17.0f)) - 1.0f);
  float se = sinf(e);
  d[0] = cosf(a) * se;
  d[1] = sinf(a) * se;
  d[2] = cosf(e);
}

__device__ __forceinline__ float dval(int s){ return ((float)s*(1.0f/63.0f))*7.9f + 0.1f; }

__device__ __forceinline__ uint32_t pk2(float a, float b){
  return (uint32_t)__half_as_ushort(__float2half(a)) |
         ((uint32_t)__half_as_ushort(__float2half(b)) << 16);
}

// K1: lane = s. Each lane computes its sample's full hidden vector h[64]
// (independent dense FMA, wave-uniform weights), attn, transmittance via one
// wave-wide multiplicative scan. Verified round 2->3 (73 us -> off top-5).
__global__ __launch_bounds__(64)
void k1_rays(const float* __restrict__ rays_o, const float* __restrict__ position_tx,
             const float* __restrict__ W1, const float* __restrict__ b1,
             const float* __restrict__ w_attn,
             __half* __restrict__ wh, float* __restrict__ w_arr, int* __restrict__ delay_arr)
{
  const int br = blockIdx.x;
  const int b = br / RAYS, r = br % RAYS;
  const int lane = threadIdx.x;      // s index

  float dir[3]; ray_dir(r, dir);
  const float mn[3] = {-5.f,-5.f,-3.f}, mx[3] = {5.f,5.f,3.f};
  float ro[3], ntx[3];
  #pragma unroll
  for (int c=0;c<3;c++){
    ro[c] = rays_o[b*3+c];
    float t = position_tx[b*3+c];
    ntx[c] = 2.0f*(t - mn[c])/(mx[c]-mn[c]) - 1.0f;
  }

  const float dv = dval(lane);
  float feat[9], dd2 = 0.f;
  #pragma unroll
  for (int c=0;c<3;c++){
    float pt = ro[c] + dir[c]*dv;
    float npt = 2.0f*(pt - mn[c])/(mx[c]-mn[c]) - 1.0f;
    float ddc = ((ntx[c]-npt) + 1.0f)/2.0f*(mx[c]-mn[c]) + mn[c];
    dd2 += ddc*ddc;
    feat[c]   = npt;
    feat[3+c] = -dir[c];
    feat[6+c] = ntx[c];
  }

  float h[HIDN];
  float av = 0.f;
  #pragma unroll
  for (int j=0; j<HIDN; j++){
    float hj = b1[j];
    #pragma unroll
    for (int f=0; f<9; f++) hj = fmaf(feat[f], W1[f*HIDN + j], hj);
    hj = fmaxf(hj, 0.0f);
    h[j] = hj;
    av = fmaf(hj, w_attn[j], av);
  }

  float attn = fmaxf(av, 0.f) + log1pf(expf(-fabsf(av)));   // softplus
  float dist = (lane < NS-1) ? (dval(lane+1) - dv) : 1e10f;
  float alpha = 1.0f - expf(-attn*dist);

  // inclusive multiplicative scan of (1-alpha+1e-6), shifted -> transmittance
  float fac = 1.0f - alpha + 1e-6f;
  float scan = fac;
  #pragma unroll
  for (int m=1; m<64; m<<=1){
    float up = __shfl_up(scan, m, 64);
    if (lane >= m) scan *= up;
  }
  float T = __shfl_up(scan, 1, 64);
  if (lane == 0) T = 1.0f;
  float wgt = T * alpha;

  float delf = fminf(fmaxf(rintf(sqrtf(dd2)*16000.0f/343.0f), 0.f), 511.f);

  const int o2 = (b*NS + lane)*RAYS + r;
  w_arr[o2] = wgt;
  delay_arr[o2] = (int)delf;

  uint4* dst = (uint4*)(wh + (size_t)o2*HIDN);
  #pragma unroll
  for (int q=0; q<8; q++){
    uint4 v;
    v.x = pk2(wgt*h[q*8+0], wgt*h[q*8+1]);
    v.y = pk2(wgt*h[q*8+2], wgt*h[q*8+3]);
    v.z = pk2(wgt*h[q*8+4], wgt*h[q*8+5]);
    v.w = pk2(wgt*h[q*8+6], wgt*h[q*8+7]);
    dst[q] = v;
  }
}

// K23 fused: one block per (b,s), 512 threads, full 65-column bucket.
// scatter -> blocked scan -> W_sig dot + masks + path loss -> 512-pt DFT
// -> fractional-delay phase -> partial[b,s,k].
__global__ __launch_bounds__(512)
void k23_fused(const __half* __restrict__ wh, const float* __restrict__ w_arr,
               const int* __restrict__ delay_arr,
               const float* __restrict__ W_sig, const float* __restrict__ b_sig,
               float* __restrict__ partial)
{
  __shared__ float bucket[LSEQ][BSTR];   // 512*67*4 = 137,216 B
  __shared__ float part[8][BSTR];        // 2,144 B
  __shared__ float2 tw[LSEQ];            // 4,096 B
  __shared__ float gs[LSEQ];             // 2,048 B  (total 145,504 B)

  const int bsid = blockIdx.x;
  const int b = bsid / NS, s = bsid % NS;
  const int tid = threadIdx.x;
  const int obase = bsid * RAYS;

  // zero bucket
  for (int i = tid; i < LSEQ*BSTR; i += 512) (&bucket[0][0])[i] = 0.f;
  // twiddle table (independent of bucket; before barrier)
  {
    float sv, cv;
    sincosf(-(TWO_PI_F/512.0f)*(float)tid, &sv, &cv);
    tw[tid] = make_float2(cv, sv);
  }
  __syncthreads();

  // scatter: 16 slices x 32 j-pairs; packed uint loads (2 halves per thread)
  {
    const int jp = tid & 31, slice = tid >> 5;
    const uint32_t* whu = (const uint32_t*)wh;
    for (int r = slice; r < RAYS; r += 16){
      int o2 = obase + r;
      int d = delay_arr[o2];                        // broadcast across 32 lanes
      uint32_t v = whu[(size_t)o2*(HIDN/2) + jp];
      atomicAdd(&bucket[d][2*jp],   __half2float(__ushort_as_half((ushort)(v & 0xFFFF))));
      atomicAdd(&bucket[d][2*jp+1], __half2float(__ushort_as_half((ushort)(v >> 16))));
      if (jp == 31) atomicAdd(&bucket[d][64], w_arr[o2]);
    }
  }
  __syncthreads();

  // blocked inclusive scan over delay: 8 segs x 64 rows; col 63's thread also
  // scans the w column (col 64).
  {
    const int seg = tid >> 6, col = tid & 63, d0 = seg*64;
    float run = 0.f;
    for (int k=0;k<64;k++){ run += bucket[d0+k][col]; bucket[d0+k][col] = run; }
    part[seg][col] = run;
    if (col == 63){
      float runw = 0.f;
      for (int k=0;k<64;k++){ runw += bucket[d0+k][64]; bucket[d0+k][64] = runw; }
      part[seg][64] = runw;
    }
  }
  __syncthreads();
  {
    const int seg = tid >> 6, col = tid & 63, d0 = seg*64;
    float off = 0.f;
    for (int t=0;t<seg;t++) off += part[t][col];
    for (int k=0;k<64;k++) bucket[d0+k][col] += off;
    if (col == 63){
      float offw = 0.f;
      for (int t=0;t<seg;t++) offw += part[t][64];
      for (int k=0;k<64;k++) bucket[d0+k][64] += offw;
    }
  }
  __syncthreads();

  // per-l dot with W_sig + b_sig*Wcum, masks, path loss -> gs[l]
  const float dv = dval(s);
  const float shiftf = rintf((16000.0f*dv)/343.0f);
  const int shift = (int)shiftf;
  {
    const int l = tid;
    if (l < LSEQ){
      float acc = b_sig[l] * bucket[l][64];
      #pragma unroll 16
      for (int j=0;j<HIDN;j++) acc += bucket[l][j] * W_sig[j*LSEQ + l];
      float mt = (((float)(LSEQ-1-l)) - shiftf > 0.f) ? 1.f : 0.f;
      int pli = shift + l;
      if (pli < 4) pli = 5;                       // path_loss[:4] = path_loss[5]
      float ideal = ((float)pli/16000.0f)*343.0f;
      gs[l] = acc * mt / (ideal + 0.001f);
    }
  }
  __syncthreads();

  // 512-point DFT for bins 0..256 + fractional-delay phase
  const float c = (16000.0f*dv)/343.0f;
  if (tid < NF){
    const int k = tid;
    float re = 0.f, im = 0.f;
    for (int l=0; l<LSEQ; l++){
      int t = (k*l) & (LSEQ-1);
      float2 w = tw[t];
      float gv = gs[l];
      re = fmaf(gv, w.x, re);
      im = fmaf(gv, w.y, im);
    }
    float ang = -(TWO_PI_F/512.0f)*((float)k*c);
    float sp, cp; sincosf(ang, &sp, &cp);
    size_t o = ((size_t)bsid*NF + k)*2;
    partial[o]   = re*cp - im*sp;
    partial[o+1] = re*sp + im*cp;
  }
}

// K4: deterministic reduction over s (4-way chunked + LDS combine).
__global__ __launch_bounds__(256)
void k4_reduce(const float* __restrict__ partial, float* __restrict__ out)
{
  __shared__ float red[4][64];
  const int tid = threadIdx.x;
  const int ol = tid & 63, chunk = tid >> 6;
  const int o = blockIdx.x*64 + ol;
  float acc = 0.f;
  if (o < BS*NF*2){
    int b = o / (NF*2);
    int rem = o - b*(NF*2);
    int k = rem >> 1, comp = rem & 1;
    for (int s=chunk; s<NS; s+=4)
      acc += partial[((size_t)(b*NS + s)*NF + k)*2 + comp];
  }
  red[chunk][ol] = acc;
  __syncthreads();
  if (tid < 64 && o < BS*NF*2){
    int b = o / (NF*2);
    int rem = o - b*(NF*2);
    int k = rem >> 1, comp = rem & 1;
    out[(b*NF + k)*2 + comp] = red[0][ol]+red[1][ol]+red[2][ol]+red[3][ol];
  }
}

extern "C" void kernel_launch(void* const* d_in, const int* in_sizes, int n_in,
                              void* d_out, int out_size, void* d_ws, size_t ws_size,
                              hipStream_t stream)
{
  const float* rays_o      = (const float*)d_in[0];
  const float* position_tx = (const float*)d_in[1];
  const float* W1          = (const float*)d_in[2];
  const float* b1          = (const float*)d_in[3];
  const float* w_attn      = (const float*)d_in[4];
  const float* W_sig       = (const float*)d_in[5];
  const float* b_sig       = (const float*)d_in[6];
  float* out = (float*)d_out;

  // workspace layout (~9.5 MB total)
  char* ws = (char*)d_ws;
  __half* wh       = (__half*)ws;                               // 2*64*514*64*2B = 8,421,376
  float* w_arr     = (float*)(ws + 8421376);                    // 263,168
  int*   delay_arr = (int*)  (ws + 8421376 + 263168);           // 263,168
  float* partial   = (float*)(ws + 8421376 + 2*263168);         // 2*64*257*2*4 = 526,336

  k1_rays  <<<BS*RAYS,          64, 0, stream>>>(rays_o, position_tx, W1, b1, w_attn,
                                                 wh, w_arr, delay_arr);
  k23_fused<<<BS*NS,           512, 0, stream>>>(wh, w_arr, delay_arr, W_sig, b_sig, partial);
  k4_reduce<<<(BS*NF*2+63)/64, 256, 0, stream>>>(partial, out);
}

// Round 5
// 71.840 us; speedup vs baseline: 1.2120x; 1.2120x over previous
//
#include <hip/hip_runtime.h>
#include <hip/hip_fp16.h>
#include <stdint.h>
#include <math.h>

#define BS    2
#define RAYS  514
#define NS    64
#define LSEQ  512
#define NF    257
#define HIDN  64
#define SPLIT 4
#define JC    16      // hidden columns per k2 block
#define LQ    128     // l-range per k3 block (quarter)

#define TWO_PI_F 6.28318530717958647692f

__device__ __forceinline__ uint32_t rotl32(uint32_t x, int d){ return (x<<d)|(x>>(32-d)); }

__device__ __forceinline__ void tf_rounds4(uint32_t& x0, uint32_t& x1, int a, int b, int c, int d){
  x0+=x1; x1=rotl32(x1,a); x1^=x0;
  x0+=x1; x1=rotl32(x1,b); x1^=x0;
  x0+=x1; x1=rotl32(x1,c); x1^=x0;
  x0+=x1; x1=rotl32(x1,d); x1^=x0;
}

// Threefry-2x32, 20 rounds, matching jax._src.prng.threefry2x32
__device__ void threefry2x32(uint32_t k0, uint32_t k1, uint32_t x0, uint32_t x1,
                             uint32_t& o0, uint32_t& o1)
{
  const uint32_t ks2 = k0 ^ k1 ^ 0x1BD11BDAu;
  x0 += k0; x1 += k1;
  tf_rounds4(x0,x1,13,15,26,6);   x0+=k1;  x1+=ks2+1u;
  tf_rounds4(x0,x1,17,29,16,24);  x0+=ks2; x1+=k0+2u;
  tf_rounds4(x0,x1,13,15,26,6);   x0+=k0;  x1+=k1+3u;
  tf_rounds4(x0,x1,17,29,16,24);  x0+=k1;  x1+=ks2+4u;
  tf_rounds4(x0,x1,13,15,26,6);   x0+=ks2; x1+=k0+5u;
  o0 = x0; o1 = x1;
}

// Reproduces _ray_directions() for ray r (verified round 0).
__device__ void ray_dir(int r, float d[3])
{
  if (r >= 512) { d[0]=0.f; d[1]=0.f; d[2] = (r==512) ? 1.0f : -1.0f; return; }
  int i = r >> 4, j = r & 15;
  uint32_t o0, o1;
  threefry2x32(0u, 42u, 0u, (uint32_t)i, o0, o1);
  uint32_t bits = o0 ^ o1;
  float u = __uint_as_float((bits >> 9) | 0x3F800000u) - 1.0f;   // uniform [0,1)
  const float step = TWO_PI_F / 32.0f;
  float a = (float)i * step + step * u;
  float e = acosf(2.0f * ((float)(j+1) * (1.0f/17.0f)) - 1.0f);
  float se = sinf(e);
  d[0] = cosf(a) * se;
  d[1] = sinf(a) * se;
  d[2] = cosf(e);
}

__device__ __forceinline__ float dval(int s){ return ((float)s*(1.0f/63.0f))*7.9f + 0.1f; }

__device__ __forceinline__ uint32_t pk2(float a, float b){
  return (uint32_t)__half_as_ushort(__float2half(a)) |
         ((uint32_t)__half_as_ushort(__float2half(b)) << 16);
}

// K1: lane = s. Each lane computes its sample's full hidden vector h[64]
// (independent dense FMA, wave-uniform weights), attn, transmittance via one
// wave-wide multiplicative scan. Also zeroes g and out for this graph replay
// (stream order guarantees visibility to k2/k3).
__global__ __launch_bounds__(64)
void k1_rays(const float* __restrict__ rays_o, const float* __restrict__ position_tx,
             const float* __restrict__ W1, const float* __restrict__ b1,
             const float* __restrict__ w_attn,
             __half* __restrict__ wh, float* __restrict__ w_arr, int* __restrict__ delay_arr,
             float* __restrict__ g, float* __restrict__ out)
{
  const int br = blockIdx.x;
  const int b = br / RAYS, r = br % RAYS;
  const int lane = threadIdx.x;      // s index

  // zero accumulators (65792 threads cover 65536-elem g and 1028-elem out)
  {
    int gi = br*64 + lane;
    if (gi < BS*NS*LSEQ) g[gi] = 0.f;
    if (gi < BS*NF*2) out[gi] = 0.f;
  }

  float dir[3]; ray_dir(r, dir);
  const float mn[3] = {-5.f,-5.f,-3.f}, mx[3] = {5.f,5.f,3.f};
  float ro[3], ntx[3];
  #pragma unroll
  for (int c=0;c<3;c++){
    ro[c] = rays_o[b*3+c];
    float t = position_tx[b*3+c];
    ntx[c] = 2.0f*(t - mn[c])/(mx[c]-mn[c]) - 1.0f;
  }

  const float dv = dval(lane);
  float feat[9], dd2 = 0.f;
  #pragma unroll
  for (int c=0;c<3;c++){
    float pt = ro[c] + dir[c]*dv;
    float npt = 2.0f*(pt - mn[c])/(mx[c]-mn[c]) - 1.0f;
    float ddc = ((ntx[c]-npt) + 1.0f)/2.0f*(mx[c]-mn[c]) + mn[c];
    dd2 += ddc*ddc;
    feat[c]   = npt;
    feat[3+c] = -dir[c];
    feat[6+c] = ntx[c];
  }

  float h[HIDN];
  float av = 0.f;
  #pragma unroll
  for (int j=0; j<HIDN; j++){
    float hj = b1[j];
    #pragma unroll
    for (int f=0; f<9; f++) hj = fmaf(feat[f], W1[f*HIDN + j], hj);
    hj = fmaxf(hj, 0.0f);
    h[j] = hj;
    av = fmaf(hj, w_attn[j], av);
  }

  float attn = fmaxf(av, 0.f) + log1pf(expf(-fabsf(av)));   // softplus
  float dist = (lane < NS-1) ? (dval(lane+1) - dv) : 1e10f;
  float alpha = 1.0f - expf(-attn*dist);

  // inclusive multiplicative scan of (1-alpha+1e-6), shifted -> transmittance
  float fac = 1.0f - alpha + 1e-6f;
  float scan = fac;
  #pragma unroll
  for (int m=1; m<64; m<<=1){
    float up = __shfl_up(scan, m, 64);
    if (lane >= m) scan *= up;
  }
  float T = __shfl_up(scan, 1, 64);
  if (lane == 0) T = 1.0f;
  float wgt = T * alpha;

  float delf = fminf(fmaxf(rintf(sqrtf(dd2)*16000.0f/343.0f), 0.f), 511.f);

  const int o2 = (b*NS + lane)*RAYS + r;
  w_arr[o2] = wgt;
  delay_arr[o2] = (int)delf;

  uint4* dst = (uint4*)(wh + (size_t)o2*HIDN);
  #pragma unroll
  for (int q=0; q<8; q++){
    uint4 v;
    v.x = pk2(wgt*h[q*8+0], wgt*h[q*8+1]);
    v.y = pk2(wgt*h[q*8+2], wgt*h[q*8+3]);
    v.z = pk2(wgt*h[q*8+4], wgt*h[q*8+5]);
    v.w = pk2(wgt*h[q*8+6], wgt*h[q*8+7]);
    dst[q] = v;
  }
}

// K2: per (b,s,p): delay-bucket scatter of 16 columns of w*h (+ w col),
// blocked parallel inclusive scan over delay, partial dot with W_sig chunk,
// mask + path-loss factor applied per-p (linear => exact), atomicAdd into g.
__global__ __launch_bounds__(256)
void k2_bucket(const __half* __restrict__ wh, const float* __restrict__ w_arr,
               const int* __restrict__ delay_arr,
               const float* __restrict__ W_sig, const float* __restrict__ b_sig,
               float* __restrict__ g)
{
  __shared__ float bucket[LSEQ][JC+1];   // col JC = w column; 512*17*4 = 34,816 B
  __shared__ float part[16][JC+1];
  const int blk = blockIdx.x;
  const int bsid = blk / SPLIT, p = blk % SPLIT;
  const int b = bsid / NS, s = bsid % NS;
  const int tid = threadIdx.x;
  const int j = tid & 15, slice = tid >> 4;   // 16 slices x 16 cols
  const int jbase = p*JC;
  const int obase = (b*NS + s)*RAYS;

  for (int i = tid; i < LSEQ*(JC+1); i += 256) (&bucket[0][0])[i] = 0.f;
  __syncthreads();

  // scatter (LDS float atomics are fire-and-forget)
  for (int r = slice; r < RAYS; r += 16){
    int o2 = obase + r;
    int d = delay_arr[o2];                       // broadcast across 16 j-lanes
    float v = __half2float(wh[(size_t)o2*HIDN + jbase + j]);
    atomicAdd(&bucket[d][j], v);
    if (j == 15) atomicAdd(&bucket[d][JC], w_arr[o2]);
  }
  __syncthreads();

  // blocked inclusive scan: 16 segs of 32 rows
  {
    const int seg = slice, d0 = seg*32;
    float run = 0.f;
    for (int k=0;k<32;k++){ run += bucket[d0+k][j]; bucket[d0+k][j] = run; }
    part[seg][j] = run;
    if (j == 15){
      float runw = 0.f;
      for (int k=0;k<32;k++){ runw += bucket[d0+k][JC]; bucket[d0+k][JC] = runw; }
      part[seg][JC] = runw;
    }
  }
  __syncthreads();
  {
    const int seg = slice, d0 = seg*32;
    float off = 0.f;
    for (int t=0;t<seg;t++) off += part[t][j];
    for (int k=0;k<32;k++) bucket[d0+k][j] += off;
    if (j == 15){
      float offw = 0.f;
      for (int t=0;t<seg;t++) offw += part[t][JC];
      for (int k=0;k<32;k++) bucket[d0+k][JC] += offw;
    }
  }
  __syncthreads();

  // partial dot + factor -> atomicAdd into g[bsid][l]
  const float dv = dval(s);
  const float shiftf = rintf((16000.0f*dv)/343.0f);
  const int shift = (int)shiftf;
  for (int l = tid; l < LSEQ; l += 256){
    float mt = (((float)(LSEQ-1-l)) - shiftf > 0.f) ? 1.f : 0.f;
    if (mt > 0.f){
      float acc = 0.f;
      #pragma unroll
      for (int jj=0;jj<JC;jj++) acc += bucket[l][jj] * W_sig[(jbase+jj)*LSEQ + l];
      if (p == 0) acc += b_sig[l] * bucket[l][JC];
      int pli = shift + l;
      if (pli < 4) pli = 5;                     // path_loss[:4] = path_loss[5]
      float ideal = ((float)pli/16000.0f)*343.0f;
      atomicAdd(&g[bsid*LSEQ + l], acc / (ideal + 0.001f));
    }
  }
}

// K3: per (b,s,quarter): 128-pt partial DFT of g via register twiddle
// recurrence (no LDS table -> no bank conflicts), fractional-delay phase,
// atomicAdd straight into out.
__global__ __launch_bounds__(320)
void k3_dft(const float* __restrict__ g, float* __restrict__ out)
{
  __shared__ float gs[LQ];
  const int blk = blockIdx.x;
  const int bsid = blk >> 2, quarter = blk & 3;
  const int b = bsid / NS, s = bsid % NS;
  const int tid = threadIdx.x;
  const int l0 = quarter*LQ;

  if (tid < LQ) gs[tid] = g[bsid*LSEQ + l0 + tid];
  __syncthreads();

  if (tid < NF){
    const int k = tid;
    // w = e^{-i*2pi*(k*l0 mod 512)/512}; step = e^{-i*2pi*k/512}
    int t0 = (k*l0) & (LSEQ-1);
    float wi, wr; sincosf(-(TWO_PI_F/512.0f)*(float)t0, &wi, &wr);
    float ss, cs; sincosf(-(TWO_PI_F/512.0f)*(float)k,  &ss, &cs);
    float re = 0.f, im = 0.f;
    for (int l=0; l<LQ; l++){
      float gv = gs[l];                          // LDS broadcast, conflict-free
      re = fmaf(gv, wr, re);
      im = fmaf(gv, wi, im);
      float nwr = wr*cs - wi*ss;
      wi = fmaf(wr, ss, wi*cs);
      wr = nwr;
    }
    float c = (16000.0f*dval(s))/343.0f;         // fractional pts2rx_idx
    float ang = -(TWO_PI_F/512.0f)*((float)k*c);
    float sp, cp; sincosf(ang, &sp, &cp);
    atomicAdd(&out[(b*NF + k)*2],     re*cp - im*sp);
    atomicAdd(&out[(b*NF + k)*2 + 1], re*sp + im*cp);
  }
}

extern "C" void kernel_launch(void* const* d_in, const int* in_sizes, int n_in,
                              void* d_out, int out_size, void* d_ws, size_t ws_size,
                              hipStream_t stream)
{
  const float* rays_o      = (const float*)d_in[0];
  const float* position_tx = (const float*)d_in[1];
  const float* W1          = (const float*)d_in[2];
  const float* b1          = (const float*)d_in[3];
  const float* w_attn      = (const float*)d_in[4];
  const float* W_sig       = (const float*)d_in[5];
  const float* b_sig       = (const float*)d_in[6];
  float* out = (float*)d_out;

  // workspace layout (~9.2 MB total)
  char* ws = (char*)d_ws;
  __half* wh       = (__half*)ws;                               // 2*64*514*64*2B = 8,421,376
  float* w_arr     = (float*)(ws + 8421376);                    // 263,168
  int*   delay_arr = (int*)  (ws + 8421376 + 263168);           // 263,168
  float* g         = (float*)(ws + 8421376 + 2*263168);         // 2*64*512*4 = 262,144

  k1_rays  <<<BS*RAYS,    64, 0, stream>>>(rays_o, position_tx, W1, b1, w_attn,
                                           wh, w_arr, delay_arr, g, out);
  k2_bucket<<<BS*NS*SPLIT, 256, 0, stream>>>(wh, w_arr, delay_arr, W_sig, b_sig, g);
  k3_dft   <<<BS*NS*4,    320, 0, stream>>>(g, out);
}

// Round 6
// 70.944 us; speedup vs baseline: 1.2273x; 1.0126x over previous
//
#include <hip/hip_runtime.h>
#include <hip/hip_fp16.h>
#include <stdint.h>
#include <math.h>

#define BS    2
#define RAYS  514
#define NS    64
#define LSEQ  512
#define NF    257
#define HIDN  64
#define SPLIT 4
#define JC    16      // hidden columns per k2 block

#define TWO_PI_F 6.28318530717958647692f

__device__ __forceinline__ uint32_t rotl32(uint32_t x, int d){ return (x<<d)|(x>>(32-d)); }

__device__ __forceinline__ void tf_rounds4(uint32_t& x0, uint32_t& x1, int a, int b, int c, int d){
  x0+=x1; x1=rotl32(x1,a); x1^=x0;
  x0+=x1; x1=rotl32(x1,b); x1^=x0;
  x0+=x1; x1=rotl32(x1,c); x1^=x0;
  x0+=x1; x1=rotl32(x1,d); x1^=x0;
}

// Threefry-2x32, 20 rounds, matching jax._src.prng.threefry2x32
__device__ void threefry2x32(uint32_t k0, uint32_t k1, uint32_t x0, uint32_t x1,
                             uint32_t& o0, uint32_t& o1)
{
  const uint32_t ks2 = k0 ^ k1 ^ 0x1BD11BDAu;
  x0 += k0; x1 += k1;
  tf_rounds4(x0,x1,13,15,26,6);   x0+=k1;  x1+=ks2+1u;
  tf_rounds4(x0,x1,17,29,16,24);  x0+=ks2; x1+=k0+2u;
  tf_rounds4(x0,x1,13,15,26,6);   x0+=k0;  x1+=k1+3u;
  tf_rounds4(x0,x1,17,29,16,24);  x0+=k1;  x1+=ks2+4u;
  tf_rounds4(x0,x1,13,15,26,6);   x0+=ks2; x1+=k0+5u;
  o0 = x0; o1 = x1;
}

// Reproduces _ray_directions() for ray r (verified round 0).
__device__ void ray_dir(int r, float d[3])
{
  if (r >= 512) { d[0]=0.f; d[1]=0.f; d[2] = (r==512) ? 1.0f : -1.0f; return; }
  int i = r >> 4, j = r & 15;
  uint32_t o0, o1;
  threefry2x32(0u, 42u, 0u, (uint32_t)i, o0, o1);
  uint32_t bits = o0 ^ o1;
  float u = __uint_as_float((bits >> 9) | 0x3F800000u) - 1.0f;   // uniform [0,1)
  const float step = TWO_PI_F / 32.0f;
  float a = (float)i * step + step * u;
  float e = acosf(2.0f * ((float)(j+1) * (1.0f/17.0f)) - 1.0f);
  float se = sinf(e);
  d[0] = cosf(a) * se;
  d[1] = sinf(a) * se;
  d[2] = cosf(e);
}

__device__ __forceinline__ float dval(int s){ return ((float)s*(1.0f/63.0f))*7.9f + 0.1f; }

__device__ __forceinline__ uint32_t pk2(float a, float b){
  return (uint32_t)__half_as_ushort(__float2half(a)) |
         ((uint32_t)__half_as_ushort(__float2half(b)) << 16);
}

// K1: 4 waves/block, one (b,r) per wave; lane = s. Each lane computes its
// sample's hidden vector h[64] (dense FMA, wave-uniform weights), attn, and
// transmittance via one wave-wide multiplicative scan. Zeroes out[] for this
// replay (stream order guarantees visibility to k2).
__global__ __launch_bounds__(256)
void k1_rays(const float* __restrict__ rays_o, const float* __restrict__ position_tx,
             const float* __restrict__ W1, const float* __restrict__ b1,
             const float* __restrict__ w_attn,
             __half* __restrict__ wh, float* __restrict__ w_arr, int* __restrict__ delay_arr,
             float* __restrict__ out)
{
  const int tid = threadIdx.x;
  const int wid = tid >> 6, lane = tid & 63;       // lane = s index
  const int br = blockIdx.x*4 + wid;               // 257*4 = 1028 = BS*RAYS
  const int b = br / RAYS, r = br % RAYS;

  { // zero the atomic output accumulator
    int gi = blockIdx.x*256 + tid;
    if (gi < BS*NF*2) out[gi] = 0.f;
  }

  float dir[3]; ray_dir(r, dir);
  const float mn[3] = {-5.f,-5.f,-3.f}, mx[3] = {5.f,5.f,3.f};
  float ro[3], ntx[3];
  #pragma unroll
  for (int c=0;c<3;c++){
    ro[c] = rays_o[b*3+c];
    float t = position_tx[b*3+c];
    ntx[c] = 2.0f*(t - mn[c])/(mx[c]-mn[c]) - 1.0f;
  }

  const float dv = dval(lane);
  float feat[9], dd2 = 0.f;
  #pragma unroll
  for (int c=0;c<3;c++){
    float pt = ro[c] + dir[c]*dv;
    float npt = 2.0f*(pt - mn[c])/(mx[c]-mn[c]) - 1.0f;
    float ddc = ((ntx[c]-npt) + 1.0f)/2.0f*(mx[c]-mn[c]) + mn[c];
    dd2 += ddc*ddc;
    feat[c]   = npt;
    feat[3+c] = -dir[c];
    feat[6+c] = ntx[c];
  }

  float h[HIDN];
  float av = 0.f;
  #pragma unroll
  for (int j=0; j<HIDN; j++){
    float hj = b1[j];
    #pragma unroll
    for (int f=0; f<9; f++) hj = fmaf(feat[f], W1[f*HIDN + j], hj);
    hj = fmaxf(hj, 0.0f);
    h[j] = hj;
    av = fmaf(hj, w_attn[j], av);
  }

  float attn = fmaxf(av, 0.f) + log1pf(expf(-fabsf(av)));   // softplus
  float dist = (lane < NS-1) ? (dval(lane+1) - dv) : 1e10f;
  float alpha = 1.0f - expf(-attn*dist);

  // inclusive multiplicative scan of (1-alpha+1e-6), shifted -> transmittance
  float fac = 1.0f - alpha + 1e-6f;
  float scan = fac;
  #pragma unroll
  for (int m=1; m<64; m<<=1){
    float up = __shfl_up(scan, m, 64);
    if (lane >= m) scan *= up;
  }
  float T = __shfl_up(scan, 1, 64);
  if (lane == 0) T = 1.0f;
  float wgt = T * alpha;

  float delf = fminf(fmaxf(rintf(sqrtf(dd2)*16000.0f/343.0f), 0.f), 511.f);

  const int o2 = (b*NS + lane)*RAYS + r;
  w_arr[o2] = wgt;
  delay_arr[o2] = (int)delf;

  uint4* dst = (uint4*)(wh + (size_t)o2*HIDN);
  #pragma unroll
  for (int q=0; q<8; q++){
    uint4 v;
    v.x = pk2(wgt*h[q*8+0], wgt*h[q*8+1]);
    v.y = pk2(wgt*h[q*8+2], wgt*h[q*8+3]);
    v.z = pk2(wgt*h[q*8+4], wgt*h[q*8+5]);
    v.w = pk2(wgt*h[q*8+6], wgt*h[q*8+7]);
    dst[q] = v;
  }
}

// K2 fused: per (b,s,p): delay-bucket scatter of 16 columns of w*h (+ w col,
// p==0 only), blocked inclusive scan over delay, partial dot with W_sig chunk
// + mask + path loss -> partial g_p[512] in LDS, then (DFT is linear) a full
// 512-pt DFT of g_p per bin with register twiddle recurrence (reseeded every
// 128 steps), fractional-delay phase, atomicAdd into out.
__global__ __launch_bounds__(320)
void k2_fused(const __half* __restrict__ wh, const float* __restrict__ w_arr,
              const int* __restrict__ delay_arr,
              const float* __restrict__ W_sig, const float* __restrict__ b_sig,
              float* __restrict__ out)
{
  __shared__ float bucket[LSEQ][JC+1];   // col JC = w column; 512*17*4 = 34,816 B
  __shared__ float part[16][JC+1];
  __shared__ float gs[LSEQ];             // partial g_p (2 KB); total ~38 KB
  const int blk = blockIdx.x;
  const int bsid = blk / SPLIT, p = blk % SPLIT;
  const int b = bsid / NS, s = bsid % NS;
  const int tid = threadIdx.x;
  const int j = tid & 15, slice = tid >> 4;   // (tid<256): 16 slices x 16 cols
  const int jbase = p*JC;
  const int obase = bsid * RAYS;

  for (int i = tid; i < LSEQ*(JC+1); i += 320) (&bucket[0][0])[i] = 0.f;
  __syncthreads();

  // scatter (LDS float atomics are fire-and-forget)
  if (tid < 256){
    for (int r = slice; r < RAYS; r += 16){
      int o2 = obase + r;
      int d = delay_arr[o2];                       // broadcast across 16 j-lanes
      float v = __half2float(wh[(size_t)o2*HIDN + jbase + j]);
      atomicAdd(&bucket[d][j], v);
      if (p == 0 && j == 15) atomicAdd(&bucket[d][JC], w_arr[o2]);
    }
  }
  __syncthreads();

  // blocked inclusive scan: 16 segs of 32 rows (w col scanned by j==15, p==0)
  if (tid < 256){
    const int seg = slice, d0 = seg*32;
    float run = 0.f;
    for (int k=0;k<32;k++){ run += bucket[d0+k][j]; bucket[d0+k][j] = run; }
    part[seg][j] = run;
    if (p == 0 && j == 15){
      float runw = 0.f;
      for (int k=0;k<32;k++){ runw += bucket[d0+k][JC]; bucket[d0+k][JC] = runw; }
      part[seg][JC] = runw;
    }
  }
  __syncthreads();
  if (tid < 256){
    const int seg = slice, d0 = seg*32;
    float off = 0.f;
    for (int t=0;t<seg;t++) off += part[t][j];
    for (int k=0;k<32;k++) bucket[d0+k][j] += off;
    if (p == 0 && j == 15){
      float offw = 0.f;
      for (int t=0;t<seg;t++) offw += part[t][JC];
      for (int k=0;k<32;k++) bucket[d0+k][JC] += offw;
    }
  }
  __syncthreads();

  // partial dot + mask + path loss -> gs[l]
  const float dv = dval(s);
  const float shiftf = rintf((16000.0f*dv)/343.0f);
  const int shift = (int)shiftf;
  if (tid < 256){
    for (int l = tid; l < LSEQ; l += 256){
      float mt = (((float)(LSEQ-1-l)) - shiftf > 0.f) ? 1.f : 0.f;
      float v = 0.f;
      if (mt > 0.f){
        float acc = 0.f;
        #pragma unroll
        for (int jj=0;jj<JC;jj++) acc += bucket[l][jj] * W_sig[(jbase+jj)*LSEQ + l];
        if (p == 0) acc += b_sig[l] * bucket[l][JC];
        int pli = shift + l;
        if (pli < 4) pli = 5;                     // path_loss[:4] = path_loss[5]
        float ideal = ((float)pli/16000.0f)*343.0f;
        v = acc / (ideal + 0.001f);
      }
      gs[l] = v;
    }
  }
  __syncthreads();

  // full 512-pt DFT of g_p for bin k=tid (0..256), register twiddle recurrence
  if (tid < NF){
    const int k = tid;
    float ss, cs; sincosf(-(TWO_PI_F/512.0f)*(float)k, &ss, &cs);
    float re = 0.f, im = 0.f;
    #pragma unroll
    for (int chunk=0; chunk<4; chunk++){
      int t0 = (k*(chunk*128)) & (LSEQ-1);
      float wi, wr; sincosf(-(TWO_PI_F/512.0f)*(float)t0, &wi, &wr);
      for (int l=0; l<128; l++){
        float gv = gs[chunk*128 + l];              // LDS broadcast, conflict-free
        re = fmaf(gv, wr, re);
        im = fmaf(gv, wi, im);
        float nwr = wr*cs - wi*ss;
        wi = fmaf(wr, ss, wi*cs);
        wr = nwr;
      }
    }
    float c = (16000.0f*dv)/343.0f;                // fractional pts2rx_idx
    float ang = -(TWO_PI_F/512.0f)*((float)k*c);
    float sp, cp; sincosf(ang, &sp, &cp);
    atomicAdd(&out[(b*NF + k)*2],     re*cp - im*sp);
    atomicAdd(&out[(b*NF + k)*2 + 1], re*sp + im*cp);
  }
}

extern "C" void kernel_launch(void* const* d_in, const int* in_sizes, int n_in,
                              void* d_out, int out_size, void* d_ws, size_t ws_size,
                              hipStream_t stream)
{
  const float* rays_o      = (const float*)d_in[0];
  const float* position_tx = (const float*)d_in[1];
  const float* W1          = (const float*)d_in[2];
  const float* b1          = (const float*)d_in[3];
  const float* w_attn      = (const float*)d_in[4];
  const float* W_sig       = (const float*)d_in[5];
  const float* b_sig       = (const float*)d_in[6];
  float* out = (float*)d_out;

  // workspace layout (~8.9 MB total)
  char* ws = (char*)d_ws;
  __half* wh       = (__half*)ws;                               // 2*64*514*64*2B = 8,421,376
  float* w_arr     = (float*)(ws + 8421376);                    // 263,168
  int*   delay_arr = (int*)  (ws + 8421376 + 263168);           // 263,168

  k1_rays <<<(BS*RAYS)/4, 256, 0, stream>>>(rays_o, position_tx, W1, b1, w_attn,
                                            wh, w_arr, delay_arr, out);
  k2_fused<<<BS*NS*SPLIT, 320, 0, stream>>>(wh, w_arr, delay_arr, W_sig, b_sig, out);
}

// Round 7
// 55.439 us; speedup vs baseline: 1.5706x; 1.2797x over previous
//
#include <hip/hip_runtime.h>
#include <hip/hip_fp16.h>
#include <stdint.h>
#include <math.h>

#define BS    2
#define RAYS  514
#define NS    64
#define LSEQ  512
#define NF    257
#define HIDN  64
#define SPLIT 4
#define JC    16      // hidden columns per k2 block

#define TWO_PI_F 6.28318530717958647692f

__device__ __forceinline__ uint32_t rotl32(uint32_t x, int d){ return (x<<d)|(x>>(32-d)); }

__device__ __forceinline__ void tf_rounds4(uint32_t& x0, uint32_t& x1, int a, int b, int c, int d){
  x0+=x1; x1=rotl32(x1,a); x1^=x0;
  x0+=x1; x1=rotl32(x1,b); x1^=x0;
  x0+=x1; x1=rotl32(x1,c); x1^=x0;
  x0+=x1; x1=rotl32(x1,d); x1^=x0;
}

// Threefry-2x32, 20 rounds, matching jax._src.prng.threefry2x32
__device__ void threefry2x32(uint32_t k0, uint32_t k1, uint32_t x0, uint32_t x1,
                             uint32_t& o0, uint32_t& o1)
{
  const uint32_t ks2 = k0 ^ k1 ^ 0x1BD11BDAu;
  x0 += k0; x1 += k1;
  tf_rounds4(x0,x1,13,15,26,6);   x0+=k1;  x1+=ks2+1u;
  tf_rounds4(x0,x1,17,29,16,24);  x0+=ks2; x1+=k0+2u;
  tf_rounds4(x0,x1,13,15,26,6);   x0+=k0;  x1+=k1+3u;
  tf_rounds4(x0,x1,17,29,16,24);  x0+=k1;  x1+=ks2+4u;
  tf_rounds4(x0,x1,13,15,26,6);   x0+=ks2; x1+=k0+5u;
  o0 = x0; o1 = x1;
}

// Reproduces _ray_directions() for ray r (verified round 0).
__device__ void ray_dir(int r, float d[3])
{
  if (r >= 512) { d[0]=0.f; d[1]=0.f; d[2] = (r==512) ? 1.0f : -1.0f; return; }
  int i = r >> 4, j = r & 15;
  uint32_t o0, o1;
  threefry2x32(0u, 42u, 0u, (uint32_t)i, o0, o1);
  uint32_t bits = o0 ^ o1;
  float u = __uint_as_float((bits >> 9) | 0x3F800000u) - 1.0f;   // uniform [0,1)
  const float step = TWO_PI_F / 32.0f;
  float a = (float)i * step + step * u;
  float e = acosf(2.0f * ((float)(j+1) * (1.0f/17.0f)) - 1.0f);
  float se = sinf(e);
  d[0] = cosf(a) * se;
  d[1] = sinf(a) * se;
  d[2] = cosf(e);
}

__device__ __forceinline__ float dval(int s){ return ((float)s*(1.0f/63.0f))*7.9f + 0.1f; }

__device__ __forceinline__ uint32_t pk2(float a, float b){
  return (uint32_t)__half_as_ushort(__float2half(a)) |
         ((uint32_t)__half_as_ushort(__float2half(b)) << 16);
}

__device__ __forceinline__ float h2lo(uint32_t u){ return __half2float(__ushort_as_half((ushort)(u & 0xFFFF))); }
__device__ __forceinline__ float h2hi(uint32_t u){ return __half2float(__ushort_as_half((ushort)(u >> 16))); }

// K1: 4 waves/block, one (b,r) per wave; lane = s. Stores wh in the
// p-quartered layout [p][bsid][r][16] so k2's scatter loads are contiguous.
// Also zeroes g and out for this replay (stream order covers k2/k3).
__global__ __launch_bounds__(256)
void k1_rays(const float* __restrict__ rays_o, const float* __restrict__ position_tx,
             const float* __restrict__ W1, const float* __restrict__ b1,
             const float* __restrict__ w_attn,
             __half* __restrict__ wh, float* __restrict__ w_arr, int* __restrict__ delay_arr,
             float* __restrict__ g, float* __restrict__ out)
{
  const int tid = threadIdx.x;
  const int wid = tid >> 6, lane = tid & 63;       // lane = s index
  const int br = blockIdx.x*4 + wid;               // 257*4 = 1028 = BS*RAYS
  const int b = br / RAYS, r = br % RAYS;

  { // zero the atomic accumulators (65792 threads cover g:65536 and out:1028)
    int gi = blockIdx.x*256 + tid;
    if (gi < BS*NS*LSEQ) g[gi] = 0.f;
    if (gi < BS*NF*2) out[gi] = 0.f;
  }

  float dir[3]; ray_dir(r, dir);
  const float mn[3] = {-5.f,-5.f,-3.f}, mx[3] = {5.f,5.f,3.f};
  float ro[3], ntx[3];
  #pragma unroll
  for (int c=0;c<3;c++){
    ro[c] = rays_o[b*3+c];
    float t = position_tx[b*3+c];
    ntx[c] = 2.0f*(t - mn[c])/(mx[c]-mn[c]) - 1.0f;
  }

  const float dv = dval(lane);
  float feat[9], dd2 = 0.f;
  #pragma unroll
  for (int c=0;c<3;c++){
    float pt = ro[c] + dir[c]*dv;
    float npt = 2.0f*(pt - mn[c])/(mx[c]-mn[c]) - 1.0f;
    float ddc = ((ntx[c]-npt) + 1.0f)/2.0f*(mx[c]-mn[c]) + mn[c];
    dd2 += ddc*ddc;
    feat[c]   = npt;
    feat[3+c] = -dir[c];
    feat[6+c] = ntx[c];
  }

  float h[HIDN];
  float av = 0.f;
  #pragma unroll
  for (int j=0; j<HIDN; j++){
    float hj = b1[j];
    #pragma unroll
    for (int f=0; f<9; f++) hj = fmaf(feat[f], W1[f*HIDN + j], hj);
    hj = fmaxf(hj, 0.0f);
    h[j] = hj;
    av = fmaf(hj, w_attn[j], av);
  }

  float attn = fmaxf(av, 0.f) + log1pf(expf(-fabsf(av)));   // softplus
  float dist = (lane < NS-1) ? (dval(lane+1) - dv) : 1e10f;
  float alpha = 1.0f - expf(-attn*dist);

  // inclusive multiplicative scan of (1-alpha+1e-6), shifted -> transmittance
  float fac = 1.0f - alpha + 1e-6f;
  float scan = fac;
  #pragma unroll
  for (int m=1; m<64; m<<=1){
    float up = __shfl_up(scan, m, 64);
    if (lane >= m) scan *= up;
  }
  float T = __shfl_up(scan, 1, 64);
  if (lane == 0) T = 1.0f;
  float wgt = T * alpha;

  float delf = fminf(fmaxf(rintf(sqrtf(dd2)*16000.0f/343.0f), 0.f), 511.f);

  const int bsid = b*NS + lane;
  const int o2 = bsid*RAYS + r;
  w_arr[o2] = wgt;
  delay_arr[o2] = (int)delf;

  // quartered store: quarter p -> [p][bsid][r][16] halves (32 B per quarter)
  #pragma unroll
  for (int p=0; p<SPLIT; p++){
    uint4 v0, v1;
    v0.x = pk2(wgt*h[p*16+ 0], wgt*h[p*16+ 1]);
    v0.y = pk2(wgt*h[p*16+ 2], wgt*h[p*16+ 3]);
    v0.z = pk2(wgt*h[p*16+ 4], wgt*h[p*16+ 5]);
    v0.w = pk2(wgt*h[p*16+ 6], wgt*h[p*16+ 7]);
    v1.x = pk2(wgt*h[p*16+ 8], wgt*h[p*16+ 9]);
    v1.y = pk2(wgt*h[p*16+10], wgt*h[p*16+11]);
    v1.z = pk2(wgt*h[p*16+12], wgt*h[p*16+13]);
    v1.w = pk2(wgt*h[p*16+14], wgt*h[p*16+15]);
    uint4* dst = (uint4*)(wh + (((size_t)p*BS*NS + bsid)*RAYS + r)*16);
    dst[0] = v0; dst[1] = v1;
  }
}

// K2: per (b,s,p): coalesced b128 scatter of the contiguous 16-col slab into
// delay buckets, 2-pass blocked scan (32 segs x 16 rows), dot with W_sig
// chunk + mask + path loss, atomicAdd into g.
__global__ __launch_bounds__(512)
void k2_bucket(const __half* __restrict__ wh, const float* __restrict__ w_arr,
               const int* __restrict__ delay_arr,
               const float* __restrict__ W_sig, const float* __restrict__ b_sig,
               float* __restrict__ g)
{
  __shared__ float bucket[LSEQ][JC+1];   // col 16 = w column; 34,816 B
  __shared__ float part[32][JC+1];       // 2,176 B
  __shared__ int   delay_l[RAYS];        // 2,056 B
  __shared__ float w_l[RAYS];            // 2,056 B  (total ~41 KB)
  const int blk = blockIdx.x;
  const int bsid = blk / SPLIT, p = blk % SPLIT;
  const int tid = threadIdx.x;
  const int obase = bsid * RAYS;

  for (int i = tid; i < LSEQ*(JC+1); i += 512) (&bucket[0][0])[i] = 0.f;
  for (int i = tid; i < RAYS; i += 512){
    delay_l[i] = delay_arr[obase + i];
    if (p == 0) w_l[i] = w_arr[obase + i];
  }
  __syncthreads();

  // scatter: 1028 uint4s (2 per ray), 3 coalesced sweeps; 8 LDS atomics each
  {
    const uint4* whp = (const uint4*)(wh + ((size_t)p*BS*NS + bsid)*RAYS*16);
    #pragma unroll
    for (int i=0; i<3; i++){
      int idx = i*512 + tid;
      if (idx < RAYS*2){
        int r = idx >> 1, c8 = (idx & 1) << 3;
        uint4 v = whp[idx];
        int d = delay_l[r];
        float* brow = &bucket[d][c8];
        atomicAdd(&brow[0], h2lo(v.x)); atomicAdd(&brow[1], h2hi(v.x));
        atomicAdd(&brow[2], h2lo(v.y)); atomicAdd(&brow[3], h2hi(v.y));
        atomicAdd(&brow[4], h2lo(v.z)); atomicAdd(&brow[5], h2hi(v.z));
        atomicAdd(&brow[6], h2lo(v.w)); atomicAdd(&brow[7], h2hi(v.w));
        if (p == 0 && c8 == 0) atomicAdd(&bucket[d][JC], w_l[r]);
      }
    }
  }
  __syncthreads();

  // blocked inclusive scan: 32 segs x 16 rows (w col scanned by col==15, p==0)
  const int seg = tid >> 4, col = tid & 15, d0 = seg*16;
  {
    float run = 0.f;
    for (int k=0;k<16;k++){ run += bucket[d0+k][col]; bucket[d0+k][col] = run; }
    part[seg][col] = run;
    if (p == 0 && col == 15){
      float rw = 0.f;
      for (int k=0;k<16;k++){ rw += bucket[d0+k][JC]; bucket[d0+k][JC] = rw; }
      part[seg][JC] = rw;
    }
  }
  __syncthreads();
  {
    float off = 0.f;
    for (int t=0;t<seg;t++) off += part[t][col];
    for (int k=0;k<16;k++) bucket[d0+k][col] += off;
    if (p == 0 && col == 15){
      float ow = 0.f;
      for (int t=0;t<seg;t++) ow += part[t][JC];
      for (int k=0;k<16;k++) bucket[d0+k][JC] += ow;
    }
  }
  __syncthreads();

  // dot + mask + path loss -> atomicAdd into g[bsid][l]  (one l per thread)
  const int s = bsid % NS;
  const float dv = dval(s);
  const float shiftf = rintf((16000.0f*dv)/343.0f);
  const int shift = (int)shiftf;
  const int jbase = p*JC;
  {
    const int l = tid;
    float mt = (((float)(LSEQ-1-l)) - shiftf > 0.f) ? 1.f : 0.f;
    if (mt > 0.f){
      float acc = 0.f;
      #pragma unroll
      for (int jj=0;jj<JC;jj++) acc += bucket[l][jj] * W_sig[(jbase+jj)*LSEQ + l];
      if (p == 0) acc += b_sig[l] * bucket[l][JC];
      int pli = shift + l;
      if (pli < 4) pli = 5;                     // path_loss[:4] = path_loss[5]
      float ideal = ((float)pli/16000.0f)*343.0f;
      atomicAdd(&g[bsid*LSEQ + l], acc / (ideal + 0.001f));
    }
  }
}

// K3: per (bsid, bin-group): 512-pt DFT of g with 4 l-chunk waves x 64 bins,
// wave-uniform float4 gs reads, LDS cross-chunk reduce, fractional-delay
// phase, atomicAdd into out. Group 4 = Nyquist-ish bin 256 only.
__global__ __launch_bounds__(256)
void k3_dft(const float* __restrict__ g, float* __restrict__ out)
{
  __shared__ float4 gs4[LSEQ/4];
  __shared__ float red[4][64][2];
  const int blk = blockIdx.x;
  const int bsid = blk / 5, grp = blk % 5;
  const int b = bsid / NS, s = bsid % NS;
  const int tid = threadIdx.x;
  const int c = tid >> 6, bl = tid & 63;         // c = chunk (wave), bl = bin

  if (tid < LSEQ/4) gs4[tid] = ((const float4*)(g + bsid*LSEQ))[tid];
  __syncthreads();

  const int k = (grp < 4) ? (grp*64 + bl) : 256;
  const bool active = (grp < 4) || (bl == 0);
  float re = 0.f, im = 0.f;
  if (active){
    const int l0 = c*128;
    int t0 = (k*l0) & (LSEQ-1);
    float wi, wr; sincosf(-(TWO_PI_F/512.0f)*(float)t0, &wi, &wr);
    float ss, cs; sincosf(-(TWO_PI_F/512.0f)*(float)k,  &ss, &cs);
    for (int q=0; q<32; q++){
      float4 gv = gs4[c*32 + q];                 // wave-uniform broadcast
      #pragma unroll
      for (int e=0; e<4; e++){
        float gvv = (e==0)?gv.x:(e==1)?gv.y:(e==2)?gv.z:gv.w;
        re = fmaf(gvv, wr, re);
        im = fmaf(gvv, wi, im);
        float nr = wr*cs - wi*ss;
        wi = fmaf(wr, ss, wi*cs);
        wr = nr;
      }
    }
  }
  red[c][bl][0] = re; red[c][bl][1] = im;
  __syncthreads();

  if (tid < 64 && ((grp < 4) || tid == 0)){
    const int kk = (grp < 4) ? (grp*64 + tid) : 256;
    float rs = red[0][tid][0] + red[1][tid][0] + red[2][tid][0] + red[3][tid][0];
    float is = red[0][tid][1] + red[1][tid][1] + red[2][tid][1] + red[3][tid][1];
    float cfrac = (16000.0f*dval(s))/343.0f;     // fractional pts2rx_idx
    float ang = -(TWO_PI_F/512.0f)*((float)kk*cfrac);
    float sp, cp; sincosf(ang, &sp, &cp);
    atomicAdd(&out[(b*NF + kk)*2],     rs*cp - is*sp);
    atomicAdd(&out[(b*NF + kk)*2 + 1], rs*sp + is*cp);
  }
}

extern "C" void kernel_launch(void* const* d_in, const int* in_sizes, int n_in,
                              void* d_out, int out_size, void* d_ws, size_t ws_size,
                              hipStream_t stream)
{
  const float* rays_o      = (const float*)d_in[0];
  const float* position_tx = (const float*)d_in[1];
  const float* W1          = (const float*)d_in[2];
  const float* b1          = (const float*)d_in[3];
  const float* w_attn      = (const float*)d_in[4];
  const float* W_sig       = (const float*)d_in[5];
  const float* b_sig       = (const float*)d_in[6];
  float* out = (float*)d_out;

  // workspace layout (~9.2 MB total)
  char* ws = (char*)d_ws;
  __half* wh       = (__half*)ws;                               // 4*128*514*16*2B = 8,421,376
  float* w_arr     = (float*)(ws + 8421376);                    // 263,168
  int*   delay_arr = (int*)  (ws + 8421376 + 263168);           // 263,168
  float* g         = (float*)(ws + 8421376 + 2*263168);         // 262,144

  k1_rays  <<<(BS*RAYS)/4, 256, 0, stream>>>(rays_o, position_tx, W1, b1, w_attn,
                                             wh, w_arr, delay_arr, g, out);
  k2_bucket<<<BS*NS*SPLIT, 512, 0, stream>>>(wh, w_arr, delay_arr, W_sig, b_sig, g);
  k3_dft   <<<BS*NS*5,     256, 0, stream>>>(g, out);
}